// Round 2
// baseline (90.272 us; speedup 1.0000x reference)
//
#include <hip/hip_runtime.h>

// logits[b,r,l,t] = sum_h hs[b,l,h] * W[r,t,h] + bias[r,t]; softmax over t (3)
// M = B*L = 66048 tokens, K = 768, N = 72 (padded to 80 = 5 n-tiles of 16).
//
// Structure (round 2): barrier-free K-loop. One wave per block, one 32-token
// tile per wave, 2064 blocks. A and B fragments loaded DIRECTLY from global
// in mfma_f32_16x16x32_bf16 fragment order (lane&15 = row/col, 8 contiguous
// k at 8*(lane>>4)), converted fp32->bf16 in-register. 2-stage register
// prefetch, fully unrolled K loop (all buffer indices compile-time).
// Epilogue: wave-private LDS transpose (stride 83 = conflict-free), 3-wide
// softmax, 12B-contiguous coalesced stores.

#define HD     768
#define LSEQ   8256
#define RREL   24
#define KSTEPS 24      // 768 / 32
#define NT     5       // n-tiles of 16 covering 72 (tile 4 is half-padded)

typedef float f32x4 __attribute__((ext_vector_type(4)));
typedef short s16x8 __attribute__((ext_vector_type(8)));

__device__ __forceinline__ unsigned short f2bf(float f) {
  // round-to-nearest-even fp32 -> bf16 (finite inputs)
  unsigned int u = __builtin_bit_cast(unsigned int, f);
  u += 0x7FFFu + ((u >> 16) & 1u);
  return (unsigned short)(u >> 16);
}

__device__ __forceinline__ s16x8 pack8(float4 a, float4 b) {
  s16x8 r;
  r[0] = (short)f2bf(a.x); r[1] = (short)f2bf(a.y);
  r[2] = (short)f2bf(a.z); r[3] = (short)f2bf(a.w);
  r[4] = (short)f2bf(b.x); r[5] = (short)f2bf(b.y);
  r[6] = (short)f2bf(b.z); r[7] = (short)f2bf(b.w);
  return r;
}

// Load one prefetch stage. st/ks are compile-time after full unroll.
#define LOAD_STAGE(st, ks) do {                                   \
    const int off_ = (ks) * 32;                                   \
    abuf[st][0][0] = *(const float4*)(pA0 + off_);                \
    abuf[st][0][1] = *(const float4*)(pA0 + off_ + 4);            \
    abuf[st][1][0] = *(const float4*)(pA1 + off_);                \
    abuf[st][1][1] = *(const float4*)(pA1 + off_ + 4);            \
    _Pragma("unroll")                                             \
    for (int nt_ = 0; nt_ < 4; ++nt_) {                           \
      bbuf[st][nt_][0] = *(const float4*)(pB[nt_] + off_);        \
      bbuf[st][nt_][1] = *(const float4*)(pB[nt_] + off_ + 4);    \
    }                                                             \
    if (b4ok) {                                                   \
      bbuf[st][4][0] = *(const float4*)(pB[4] + off_);            \
      bbuf[st][4][1] = *(const float4*)(pB[4] + off_ + 4);        \
    } else {                                                      \
      bbuf[st][4][0] = make_float4(0.f, 0.f, 0.f, 0.f);           \
      bbuf[st][4][1] = make_float4(0.f, 0.f, 0.f, 0.f);           \
    }                                                             \
  } while (0)

__global__ __launch_bounds__(64, 2)
void tagging_kernel(const float* __restrict__ hs, const float* __restrict__ W,
                    const float* __restrict__ bias, float* __restrict__ out) {
  __shared__ float logits[32][83];   // stride 83: gcd(83,32)=1, writes max 2-way

  const int lane = threadIdx.x;      // 0..63 (one wave per block)
  const int m0   = blockIdx.x * 32;  // 66048 / 32 = 2064 blocks, exact
  const int fr   = lane & 15;        // fragment row (A) / col (B)
  const int ko   = (lane >> 4) * 8;  // k-octet within 32-wide k-step

  // Base pointers; per-kstep advance (128B) folds into imm offsets (<4KB).
  const float* pA0 = hs + (size_t)(m0 + fr) * HD + ko;
  const float* pA1 = pA0 + 16 * HD;
  const float* pB[NT];
  #pragma unroll
  for (int nt = 0; nt < NT; ++nt)
    pB[nt] = W + (size_t)(nt * 16 + fr) * HD + ko;
  const bool b4ok = fr < 8;          // n-tile 4 covers cols 64..79; 72..79 = pad

  float4 abuf[2][2][2];              // [stage][mtile][half]
  float4 bbuf[2][NT][2];             // [stage][ntile][half]
  f32x4  acc[2][NT] = {};            // 40 VGPR accumulator

  LOAD_STAGE(0, 0);

  #pragma unroll
  for (int ks = 0; ks < KSTEPS; ++ks) {
    const int cur = ks & 1;          // compile-time after unroll
    if (ks + 1 < KSTEPS) LOAD_STAGE((ks + 1) & 1, ks + 1);

    s16x8 af[2], bf[NT];
    af[0] = pack8(abuf[cur][0][0], abuf[cur][0][1]);
    af[1] = pack8(abuf[cur][1][0], abuf[cur][1][1]);
    #pragma unroll
    for (int nt = 0; nt < NT; ++nt)
      bf[nt] = pack8(bbuf[cur][nt][0], bbuf[cur][nt][1]);

    #pragma unroll
    for (int mt = 0; mt < 2; ++mt)
      #pragma unroll
      for (int nt = 0; nt < NT; ++nt)
        acc[mt][nt] = __builtin_amdgcn_mfma_f32_16x16x32_bf16(
            af[mt], bf[nt], acc[mt][nt], 0, 0, 0);
  }

  // ---- epilogue: wave-private LDS transpose + 3-wide softmax ----
  #pragma unroll
  for (int mt = 0; mt < 2; ++mt)
    #pragma unroll
    for (int nt = 0; nt < NT; ++nt)
      #pragma unroll
      for (int j = 0; j < 4; ++j) {
        // C/D layout: col = lane&15, row = 4*(lane>>4)+j  [guide-verified]
        logits[mt * 16 + (lane >> 4) * 4 + j][nt * 16 + fr] = acc[mt][nt][j];
      }
  __syncthreads();                   // single-wave barrier: just a waitcnt

  #pragma unroll
  for (int it = 0; it < 12; ++it) {
    int flat = it * 64 + lane;       // [0, 768) = 24 relations x 32 tokens
    int g    = flat >> 5;            // relation 0..23
    int tokl = flat & 31;
    int tok  = m0 + tokl;
    int b    = tok / LSEQ;           // magic-mul, constant divisor
    int l    = tok - b * LSEQ;
    float x0 = logits[tokl][3 * g + 0] + bias[3 * g + 0];
    float x1 = logits[tokl][3 * g + 1] + bias[3 * g + 1];
    float x2 = logits[tokl][3 * g + 2] + bias[3 * g + 2];
    float mx = fmaxf(x0, fmaxf(x1, x2));
    float e0 = __expf(x0 - mx), e1 = __expf(x1 - mx), e2 = __expf(x2 - mx);
    float inv = 1.0f / (e0 + e1 + e2);
    size_t o = ((size_t)(b * RREL + g) * LSEQ + l) * 3;
    out[o + 0] = e0 * inv;
    out[o + 1] = e1 * inv;
    out[o + 2] = e2 * inv;
  }
}

extern "C" void kernel_launch(void* const* d_in, const int* in_sizes, int n_in,
                              void* d_out, int out_size, void* d_ws, size_t ws_size,
                              hipStream_t stream) {
  (void)in_sizes; (void)n_in; (void)d_ws; (void)ws_size; (void)out_size;
  const float* hs   = (const float*)d_in[0];  // (8, 8256, 768) fp32
  const float* W    = (const float*)d_in[1];  // (24, 3, 768)   fp32
  const float* bias = (const float*)d_in[2];  // (24, 3)        fp32
  float* out = (float*)d_out;                 // (8, 24, 8256, 3) fp32

  hipLaunchKernelGGL(tagging_kernel, dim3(2064), dim3(64), 0, stream,
                     hs, W, bias, out);
}

// Round 3
// 52.640 us; speedup vs baseline: 1.7149x; 1.7149x over previous
//
#include <hip/hip_runtime.h>

// logits[b,r,l,t] = sum_h hs[b,l,h]*W[r,t,h] + bias[r,t]; softmax over t(3).
// M = 66048 tokens, K = 768, N = 72 (5 n-tiles of 16, last half-padded).
//
// Round 3: barrier-free, scatter-free.
//  - Kernel 1 (tiny): W fp32 -> bf16 MFMA-fragment-order into d_ws (123 KB,
//    L2-resident). B-frag loads in the main kernel are lane-contiguous 16B.
//  - Main kernel: 1 wave = 16 tokens, 4128 waves (16/CU). A loaded with
//    per-lane CONTIGUOUS 32B (4 lines/quarter-wave), converted to bf16 in
//    register, redistributed to fragment order via 4x ds_bpermute (wave-
//    private, no barriers). A prefetch depth-2, B depth-1. No __syncthreads
//    in the K-loop; epilogue does a wave-private LDS transpose + softmax.

#define HD     768
#define LSEQ   8256
#define RREL   24
#define KSTEPS 24      // 768/32
#define NT     5       // n-tiles of 16 covering 72 (tile 4 half-padded)
#define NCOL   72

typedef float f32x4 __attribute__((ext_vector_type(4)));
typedef short s16x8 __attribute__((ext_vector_type(8)));
typedef int   i32x4 __attribute__((ext_vector_type(4)));

__device__ __forceinline__ unsigned f2bf(float f) {
  // round-to-nearest-even fp32 -> bf16 (finite inputs)
  unsigned u = __builtin_bit_cast(unsigned, f);
  u += 0x7FFFu + ((u >> 16) & 1u);
  return u >> 16;
}
__device__ __forceinline__ int pack2(float lo, float hi) {
  return (int)(f2bf(lo) | (f2bf(hi) << 16));
}

// ---- kernel 1: W (24,3,768) fp32 -> bf16 fragment-order ws ----
// ws element idx = (ks*NT + nt)*64 + lane, holding 8 bf16:
//   col = nt*16 + (lane&15), k = ks*32 + (lane>>4)*8 + i   (0 if col>=72)
__global__ void conv_w_kernel(const float* __restrict__ W,
                              unsigned short* __restrict__ wsB) {
  int idx = blockIdx.x * 256 + threadIdx.x;       // [0, 7680)
  if (idx >= KSTEPS * NT * 64) return;
  int ks   = idx / (NT * 64);
  int rem  = idx - ks * (NT * 64);
  int nt   = rem >> 6;
  int lane = rem & 63;
  int col  = nt * 16 + (lane & 15);
  int k0   = ks * 32 + (lane >> 4) * 8;
  unsigned short v[8] = {0, 0, 0, 0, 0, 0, 0, 0};
  if (col < NCOL) {
    const float* p = W + (size_t)col * HD + k0;
    float4 a = *(const float4*)p;
    float4 b = *(const float4*)(p + 4);
    v[0] = (unsigned short)f2bf(a.x); v[1] = (unsigned short)f2bf(a.y);
    v[2] = (unsigned short)f2bf(a.z); v[3] = (unsigned short)f2bf(a.w);
    v[4] = (unsigned short)f2bf(b.x); v[5] = (unsigned short)f2bf(b.y);
    v[6] = (unsigned short)f2bf(b.z); v[7] = (unsigned short)f2bf(b.w);
  }
  *(s16x8*)(wsB + (size_t)idx * 8) = *(s16x8*)v;
}

// ---- main kernel ----
#define ALOAD(ks) do { if ((ks) < KSTEPS) {                        \
    abuf[(ks) % 3][0] = *(const float4*)(pA + (ks) * 32);          \
    abuf[(ks) % 3][1] = *(const float4*)(pA + (ks) * 32 + 4);      \
  } } while (0)

#define BLOAD_WS(ks) do { if ((ks) < KSTEPS) {                     \
    _Pragma("unroll")                                              \
    for (int nt_ = 0; nt_ < NT; ++nt_)                             \
      bbuf[(ks) & 1][nt_] = pWS[(ks) * NT * 64 + nt_ * 64 + lane]; \
  } } while (0)

#define BLOAD_FB(ks) do { if ((ks) < KSTEPS) {                     \
    _Pragma("unroll")                                              \
    for (int nt_ = 0; nt_ < 4; ++nt_) {                            \
      fbf[(ks) & 1][nt_][0] = *(const float4*)(pB[nt_] + (ks)*32); \
      fbf[(ks) & 1][nt_][1] = *(const float4*)(pB[nt_] + (ks)*32 + 4); \
    }                                                              \
    if (b4ok) {                                                    \
      fbf[(ks) & 1][4][0] = *(const float4*)(pB[4] + (ks)*32);     \
      fbf[(ks) & 1][4][1] = *(const float4*)(pB[4] + (ks)*32 + 4); \
    } else {                                                       \
      fbf[(ks) & 1][4][0] = make_float4(0.f,0.f,0.f,0.f);          \
      fbf[(ks) & 1][4][1] = make_float4(0.f,0.f,0.f,0.f);          \
    }                                                              \
  } } while (0)

template <bool USE_WS>
__global__ __launch_bounds__(256, 4)
void tagging_main(const float* __restrict__ hs, const float* __restrict__ W,
                  const float* __restrict__ bias,
                  const i32x4* __restrict__ pWS, float* __restrict__ out) {
  __shared__ float lg[4][16][84];     // per-wave logits slice, 21504 B

  const int lane = threadIdx.x & 63;
  const int wid  = threadIdx.x >> 6;
  const int m0   = (blockIdx.x * 4 + wid) * 16;   // 4128 wave-tiles exact

  // A: lane loads its own contiguous 32B: row = m0+(lane>>2), k-chunk lane&3
  const float* pA = hs + (size_t)(m0 + (lane >> 2)) * HD + (lane & 3) * 8;
  // bpermute: target lane t needs source lane 4*(t&15) + (t>>4), addr bytes
  const int bp = ((lane & 15) * 4 + (lane >> 4)) * 4;

  // fallback B pointers (fragment-order scatter loads, only if !USE_WS)
  const float* pB[NT];
  #pragma unroll
  for (int nt = 0; nt < NT; ++nt)
    pB[nt] = W + (size_t)(nt * 16 + (lane & 15)) * HD + (lane >> 4) * 8;
  const bool b4ok = (lane & 15) < 8;

  f32x4  acc[NT] = {};
  float4 abuf[3][2];                  // A depth-2 prefetch (3 slots)
  i32x4  bbuf[2][NT];                 // B depth-1 (ws path)
  float4 fbf[2][NT][2];               // B depth-1 (fallback path)

  ALOAD(0); ALOAD(1);
  if constexpr (USE_WS) { BLOAD_WS(0); } else { BLOAD_FB(0); }

  #pragma unroll
  for (int ks = 0; ks < KSTEPS; ++ks) {
    ALOAD(ks + 2);
    if constexpr (USE_WS) { BLOAD_WS(ks + 1); } else { BLOAD_FB(ks + 1); }

    // A fragment: convert this lane's 8 floats -> 4 packed-bf16 dwords,
    // then pull the 4 dwords of my fragment's source lane via bpermute.
    float4 a0 = abuf[ks % 3][0], a1 = abuf[ks % 3][1];
    int d0 = pack2(a0.x, a0.y), d1 = pack2(a0.z, a0.w);
    int d2 = pack2(a1.x, a1.y), d3 = pack2(a1.z, a1.w);
    i32x4 av;
    av[0] = __builtin_amdgcn_ds_bpermute(bp, d0);
    av[1] = __builtin_amdgcn_ds_bpermute(bp, d1);
    av[2] = __builtin_amdgcn_ds_bpermute(bp, d2);
    av[3] = __builtin_amdgcn_ds_bpermute(bp, d3);
    s16x8 af = __builtin_bit_cast(s16x8, av);

    #pragma unroll
    for (int nt = 0; nt < NT; ++nt) {
      s16x8 bf;
      if constexpr (USE_WS) {
        bf = __builtin_bit_cast(s16x8, bbuf[ks & 1][nt]);
      } else {
        float4 b0 = fbf[ks & 1][nt][0], b1 = fbf[ks & 1][nt][1];
        i32x4 bv;
        bv[0] = pack2(b0.x, b0.y); bv[1] = pack2(b0.z, b0.w);
        bv[2] = pack2(b1.x, b1.y); bv[3] = pack2(b1.z, b1.w);
        bf = __builtin_bit_cast(s16x8, bv);
      }
      acc[nt] = __builtin_amdgcn_mfma_f32_16x16x32_bf16(af, bf, acc[nt], 0, 0, 0);
    }
  }

  // ---- epilogue: wave-private LDS transpose + 3-wide softmax ----
  #pragma unroll
  for (int nt = 0; nt < NT; ++nt)
    #pragma unroll
    for (int j = 0; j < 4; ++j)   // C/D: col = lane&15, row = 4*(lane>>4)+j
      lg[wid][(lane >> 4) * 4 + j][nt * 16 + (lane & 15)] = acc[nt][j];
  __syncthreads();

  #pragma unroll
  for (int it = 0; it < 6; ++it) {
    int flat = it * 64 + lane;        // [0,384) = 24 relations x 16 tokens
    int g    = flat >> 4;
    int tokl = flat & 15;
    unsigned tok = (unsigned)(m0 + tokl);
    unsigned b   = tok / LSEQ;        // magic-mul (constant divisor)
    unsigned l   = tok - b * LSEQ;
    float x0 = lg[wid][tokl][3 * g + 0] + bias[3 * g + 0];
    float x1 = lg[wid][tokl][3 * g + 1] + bias[3 * g + 1];
    float x2 = lg[wid][tokl][3 * g + 2] + bias[3 * g + 2];
    float mx = fmaxf(x0, fmaxf(x1, x2));
    float e0 = __expf(x0 - mx), e1 = __expf(x1 - mx), e2 = __expf(x2 - mx);
    float inv = 1.0f / (e0 + e1 + e2);
    size_t o = ((size_t)(b * RREL + g) * LSEQ + l) * 3;
    out[o + 0] = e0 * inv;
    out[o + 1] = e1 * inv;
    out[o + 2] = e2 * inv;
  }
}

extern "C" void kernel_launch(void* const* d_in, const int* in_sizes, int n_in,
                              void* d_out, int out_size, void* d_ws, size_t ws_size,
                              hipStream_t stream) {
  (void)in_sizes; (void)n_in; (void)out_size;
  const float* hs   = (const float*)d_in[0];  // (8, 8256, 768) fp32
  const float* W    = (const float*)d_in[1];  // (24, 3, 768)   fp32
  const float* bias = (const float*)d_in[2];  // (24, 3)        fp32
  float* out = (float*)d_out;                 // (8, 24, 8256, 3) fp32

  const size_t needB = (size_t)KSTEPS * NT * 64 * 8 * 2;   // 122880 B
  if (d_ws && ws_size >= needB) {
    hipLaunchKernelGGL(conv_w_kernel, dim3(30), dim3(256), 0, stream,
                       W, (unsigned short*)d_ws);
    hipLaunchKernelGGL((tagging_main<true>), dim3(1032), dim3(256), 0, stream,
                       hs, W, bias, (const i32x4*)d_ws, out);
  } else {
    hipLaunchKernelGGL((tagging_main<false>), dim3(1032), dim3(256), 0, stream,
                       hs, W, bias, nullptr, out);
  }
}

// Round 5
// 46.643 us; speedup vs baseline: 1.9354x; 1.1286x over previous
//
#include <hip/hip_runtime.h>
#include <hip/hip_bf16.h>

// logits[b,r,l,t] = sum_h hs[b,l,h]*W[r,t,h] + bias[r,t]; softmax over t(3).
// M = 66048 tokens, K = 768, N = 72 (5 n-tiles of 16, last half-padded).
//
// Round 5 (= round 4 + compile fix): 32 tokens/wave (2 m-frags share every
// B fragment -> B L2 traffic halves to ~248 MB, per-token VALU halves).
// Barrier-free 1-wave blocks, 2064 blocks (8/CU). A loaded per-lane-
// contiguous (32B/lane per 16-row phase), HW v_cvt fp32->bf16,
// redistributed to MFMA fragment order with the round-3-verified
// ds_bpermute map src = 4*(t&15) + (t>>4). B preconverted to bf16
// fragment-order in d_ws by conv_w_kernel (123 KB, L2-resident).
// A prefetch depth-2, B depth-1, K-loop fully unrolled (indices static).

#define HD     768
#define LSEQ   8256
#define RREL   24
#define KSTEPS 24      // 768/32
#define NT     5       // n-tiles of 16 covering 72 (tile 4 half-padded)
#define NCOL   72

typedef float f32x4 __attribute__((ext_vector_type(4)));
typedef short s16x8 __attribute__((ext_vector_type(8)));
typedef int   i32x4 __attribute__((ext_vector_type(4)));

__device__ __forceinline__ unsigned f2bf_rne(float f) {  // used in conv_w only
  unsigned u = __builtin_bit_cast(unsigned, f);
  u += 0x7FFFu + ((u >> 16) & 1u);
  return u >> 16;
}

// hot path: HW cvt (RNE); build the packed dword with integer ops (the
// struct __hip_bfloat162 is not trivially copyable -> no bit_cast on it)
__device__ __forceinline__ int pack2(float lo, float hi) {
  unsigned l = __bfloat16_as_ushort(__float2bfloat16(lo));
  unsigned h = __bfloat16_as_ushort(__float2bfloat16(hi));
  return (int)(l | (h << 16));
}

// ---- kernel 1: W (24,3,768) fp32 -> bf16 fragment-order ws ----
// ws element idx = (ks*NT + nt)*64 + lane, holding 8 bf16:
//   col = nt*16 + (lane&15), k = ks*32 + (lane>>4)*8 + i   (0 if col>=72)
__global__ void conv_w_kernel(const float* __restrict__ W,
                              unsigned short* __restrict__ wsB) {
  int idx = blockIdx.x * 256 + threadIdx.x;       // [0, 7680)
  if (idx >= KSTEPS * NT * 64) return;
  int ks   = idx / (NT * 64);
  int rem  = idx - ks * (NT * 64);
  int nt   = rem >> 6;
  int lane = rem & 63;
  int col  = nt * 16 + (lane & 15);
  int k0   = ks * 32 + (lane >> 4) * 8;
  unsigned short v[8] = {0, 0, 0, 0, 0, 0, 0, 0};
  if (col < NCOL) {
    const float* p = W + (size_t)col * HD + k0;
    float4 a = *(const float4*)p;
    float4 b = *(const float4*)(p + 4);
    v[0] = (unsigned short)f2bf_rne(a.x); v[1] = (unsigned short)f2bf_rne(a.y);
    v[2] = (unsigned short)f2bf_rne(a.z); v[3] = (unsigned short)f2bf_rne(a.w);
    v[4] = (unsigned short)f2bf_rne(b.x); v[5] = (unsigned short)f2bf_rne(b.y);
    v[6] = (unsigned short)f2bf_rne(b.z); v[7] = (unsigned short)f2bf_rne(b.w);
  }
  *(s16x8*)(wsB + (size_t)idx * 8) = *(s16x8*)v;
}

// ---- main kernel ----
// A slot load: two 16-row phases (one per m-frag), lane-contiguous 32B each:
// phase p covers rows m0+16p+(lane>>2), floats k0+(lane&3)*8 .. +8.
#define ALOAD(ks) do { if ((ks) < KSTEPS) {                        \
    const int s_ = (ks) % 3, o_ = (ks) * 32;                       \
    abuf[s_][0][0] = *(const float4*)(pA0 + o_);                   \
    abuf[s_][0][1] = *(const float4*)(pA0 + o_ + 4);               \
    abuf[s_][1][0] = *(const float4*)(pA1 + o_);                   \
    abuf[s_][1][1] = *(const float4*)(pA1 + o_ + 4);               \
  } } while (0)

#define BLOAD_WS(ks) do { if ((ks) < KSTEPS) {                     \
    _Pragma("unroll")                                              \
    for (int nt_ = 0; nt_ < NT; ++nt_)                             \
      bbuf[(ks) & 1][nt_] = pWS[(ks) * NT * 64 + nt_ * 64 + lane]; \
  } } while (0)

#define BLOAD_FB(ks) do { if ((ks) < KSTEPS) {                     \
    _Pragma("unroll")                                              \
    for (int nt_ = 0; nt_ < 4; ++nt_) {                            \
      fbf[(ks) & 1][nt_][0] = *(const float4*)(pB[nt_] + (ks)*32); \
      fbf[(ks) & 1][nt_][1] = *(const float4*)(pB[nt_] + (ks)*32 + 4); \
    }                                                              \
    if (b4ok) {                                                    \
      fbf[(ks) & 1][4][0] = *(const float4*)(pB[4] + (ks)*32);     \
      fbf[(ks) & 1][4][1] = *(const float4*)(pB[4] + (ks)*32 + 4); \
    } else {                                                       \
      fbf[(ks) & 1][4][0] = make_float4(0.f,0.f,0.f,0.f);          \
      fbf[(ks) & 1][4][1] = make_float4(0.f,0.f,0.f,0.f);          \
    }                                                              \
  } } while (0)

template <bool USE_WS>
__global__ __launch_bounds__(64, 2)
void tagging_main(const float* __restrict__ hs, const float* __restrict__ W,
                  const float* __restrict__ bias,
                  const i32x4* __restrict__ pWS, float* __restrict__ out) {
  __shared__ float lg[32][85];        // stride 85 (== 21 mod 32, gcd 1): the
                                      // stride-85 softmax column reads are
                                      // conflict-free across 32 lanes

  const int lane = threadIdx.x;       // one wave per block
  const int m0   = blockIdx.x * 32;   // 66048/32 = 2064 blocks, exact

  const float* pA0 = hs + (size_t)(m0 + (lane >> 2)) * HD + (lane & 3) * 8;
  const float* pA1 = pA0 + 16 * HD;
  // bpermute byte addr: target lane t pulls src lane 4*(t&15) + (t>>4)
  const int bp = ((lane & 15) * 4 + (lane >> 4)) * 4;

  // fallback B pointers (fragment-order scatter, only if !USE_WS)
  const float* pB[NT];
  #pragma unroll
  for (int nt = 0; nt < NT; ++nt)
    pB[nt] = W + (size_t)(nt * 16 + (lane & 15)) * HD + (lane >> 4) * 8;
  const bool b4ok = (lane & 15) < 8;

  f32x4  acc[2][NT] = {};             // 40 VGPR
  float4 abuf[3][2][2];               // A depth-2 (3 slots x 2 mfrag x 2 f4)
  i32x4  bbuf[2][NT];                 // B depth-1 (ws path)
  float4 fbf[2][NT][2];               // B depth-1 (fallback path)

  ALOAD(0); ALOAD(1);
  if constexpr (USE_WS) { BLOAD_WS(0); } else { BLOAD_FB(0); }

  #pragma unroll
  for (int ks = 0; ks < KSTEPS; ++ks) {
    ALOAD(ks + 2);
    if constexpr (USE_WS) { BLOAD_WS(ks + 1); } else { BLOAD_FB(ks + 1); }

    s16x8 af[2];
    #pragma unroll
    for (int mt = 0; mt < 2; ++mt) {
      float4 a0 = abuf[ks % 3][mt][0], a1 = abuf[ks % 3][mt][1];
      i32x4 av;
      av[0] = __builtin_amdgcn_ds_bpermute(bp, pack2(a0.x, a0.y));
      av[1] = __builtin_amdgcn_ds_bpermute(bp, pack2(a0.z, a0.w));
      av[2] = __builtin_amdgcn_ds_bpermute(bp, pack2(a1.x, a1.y));
      av[3] = __builtin_amdgcn_ds_bpermute(bp, pack2(a1.z, a1.w));
      af[mt] = __builtin_bit_cast(s16x8, av);
    }

    #pragma unroll
    for (int nt = 0; nt < NT; ++nt) {
      s16x8 bf;
      if constexpr (USE_WS) {
        bf = __builtin_bit_cast(s16x8, bbuf[ks & 1][nt]);
      } else {
        float4 b0 = fbf[ks & 1][nt][0], b1 = fbf[ks & 1][nt][1];
        i32x4 bv;
        bv[0] = pack2(b0.x, b0.y); bv[1] = pack2(b0.z, b0.w);
        bv[2] = pack2(b1.x, b1.y); bv[3] = pack2(b1.z, b1.w);
        bf = __builtin_bit_cast(s16x8, bv);
      }
      acc[0][nt] = __builtin_amdgcn_mfma_f32_16x16x32_bf16(af[0], bf, acc[0][nt], 0, 0, 0);
      acc[1][nt] = __builtin_amdgcn_mfma_f32_16x16x32_bf16(af[1], bf, acc[1][nt], 0, 0, 0);
    }
  }

  // ---- epilogue: wave-private LDS transpose + 3-wide softmax ----
  #pragma unroll
  for (int mt = 0; mt < 2; ++mt)
    #pragma unroll
    for (int nt = 0; nt < NT; ++nt)
      #pragma unroll
      for (int j = 0; j < 4; ++j)   // C/D: col = lane&15, row = 4*(lane>>4)+j
        lg[mt * 16 + (lane >> 4) * 4 + j][nt * 16 + (lane & 15)] = acc[mt][nt][j];
  __syncthreads();                  // single wave: just the lgkmcnt drain

  const int bidx = m0 / LSEQ;       // block-uniform: 8256 % 32 == 0
  const int l0   = m0 - bidx * LSEQ;
  #pragma unroll
  for (int it = 0; it < 12; ++it) {
    int flat = it * 64 + lane;      // [0,768) = 24 relations x 32 tokens
    int g    = flat >> 5;           // relation, half-wave-uniform
    int tokl = flat & 31;
    float x0 = lg[tokl][3 * g + 0] + bias[3 * g + 0];
    float x1 = lg[tokl][3 * g + 1] + bias[3 * g + 1];
    float x2 = lg[tokl][3 * g + 2] + bias[3 * g + 2];
    float mx = fmaxf(x0, fmaxf(x1, x2));
    float e0 = __expf(x0 - mx), e1 = __expf(x1 - mx), e2 = __expf(x2 - mx);
    float inv = 1.0f / (e0 + e1 + e2);
    size_t o = ((size_t)(bidx * RREL + g) * LSEQ + l0 + tokl) * 3;
    out[o + 0] = e0 * inv;
    out[o + 1] = e1 * inv;
    out[o + 2] = e2 * inv;
  }
}

extern "C" void kernel_launch(void* const* d_in, const int* in_sizes, int n_in,
                              void* d_out, int out_size, void* d_ws, size_t ws_size,
                              hipStream_t stream) {
  (void)in_sizes; (void)n_in; (void)out_size;
  const float* hs   = (const float*)d_in[0];  // (8, 8256, 768) fp32
  const float* W    = (const float*)d_in[1];  // (24, 3, 768)   fp32
  const float* bias = (const float*)d_in[2];  // (24, 3)        fp32
  float* out = (float*)d_out;                 // (8, 24, 8256, 3) fp32

  const size_t needB = (size_t)KSTEPS * NT * 64 * 8 * 2;   // 122880 B
  if (d_ws && ws_size >= needB) {
    hipLaunchKernelGGL(conv_w_kernel, dim3(30), dim3(256), 0, stream,
                       W, (unsigned short*)d_ws);
    hipLaunchKernelGGL((tagging_main<true>), dim3(2064), dim3(64), 0, stream,
                       hs, W, bias, (const i32x4*)d_ws, out);
  } else {
    hipLaunchKernelGGL((tagging_main<false>), dim3(2064), dim3(64), 0, stream,
                       hs, W, bias, nullptr, out);
  }
}

// Round 6
// 46.394 us; speedup vs baseline: 1.9458x; 1.0054x over previous
//
#include <hip/hip_runtime.h>
#include <hip/hip_bf16.h>

// logits[b,r,l,t] = sum_h hs[b,l,h]*W[r,t,h] + bias[r,t]; softmax over t(3).
// M = 66048 tokens, K = 768, N = 72 (5 n-tiles of 16, last half-padded).
//
// Round 6 = round 5 + deeper prefetch (latency-bound theory):
//   A: depth-4 (5 rotating reg slots, was 2/3) -> ~800-1000 cy tolerance,
//      covering HBM-miss latency (~900 cy).
//   B: depth-2 (3 slots, was 1/2) -> covers L2/L3 latency.
// VGPR ~210 < 256; occupancy is grid-limited at 2 waves/SIMD regardless.
// Everything else unchanged: barrier-free 1-wave blocks (2064 = 8/CU),
// 32 tokens/wave, per-lane-contiguous A loads + verified ds_bpermute
// redistribution (src = 4*(t&15) + (t>>4)), B preconverted to bf16
// fragment-order in d_ws (123 KB, L2-resident), K-loop fully unrolled.

#define HD     768
#define LSEQ   8256
#define RREL   24
#define KSTEPS 24      // 768/32
#define NT     5       // n-tiles of 16 covering 72 (tile 4 half-padded)
#define NCOL   72

typedef float f32x4 __attribute__((ext_vector_type(4)));
typedef short s16x8 __attribute__((ext_vector_type(8)));
typedef int   i32x4 __attribute__((ext_vector_type(4)));

__device__ __forceinline__ unsigned f2bf_rne(float f) {  // used in conv_w only
  unsigned u = __builtin_bit_cast(unsigned, f);
  u += 0x7FFFu + ((u >> 16) & 1u);
  return u >> 16;
}

// hot path: HW cvt (RNE); build packed dword with integer ops
__device__ __forceinline__ int pack2(float lo, float hi) {
  unsigned l = __bfloat16_as_ushort(__float2bfloat16(lo));
  unsigned h = __bfloat16_as_ushort(__float2bfloat16(hi));
  return (int)(l | (h << 16));
}

// ---- kernel 1: W (24,3,768) fp32 -> bf16 fragment-order ws ----
// ws element idx = (ks*NT + nt)*64 + lane, holding 8 bf16:
//   col = nt*16 + (lane&15), k = ks*32 + (lane>>4)*8 + i   (0 if col>=72)
__global__ void conv_w_kernel(const float* __restrict__ W,
                              unsigned short* __restrict__ wsB) {
  int idx = blockIdx.x * 256 + threadIdx.x;       // [0, 7680)
  if (idx >= KSTEPS * NT * 64) return;
  int ks   = idx / (NT * 64);
  int rem  = idx - ks * (NT * 64);
  int nt   = rem >> 6;
  int lane = rem & 63;
  int col  = nt * 16 + (lane & 15);
  int k0   = ks * 32 + (lane >> 4) * 8;
  unsigned short v[8] = {0, 0, 0, 0, 0, 0, 0, 0};
  if (col < NCOL) {
    const float* p = W + (size_t)col * HD + k0;
    float4 a = *(const float4*)p;
    float4 b = *(const float4*)(p + 4);
    v[0] = (unsigned short)f2bf_rne(a.x); v[1] = (unsigned short)f2bf_rne(a.y);
    v[2] = (unsigned short)f2bf_rne(a.z); v[3] = (unsigned short)f2bf_rne(a.w);
    v[4] = (unsigned short)f2bf_rne(b.x); v[5] = (unsigned short)f2bf_rne(b.y);
    v[6] = (unsigned short)f2bf_rne(b.z); v[7] = (unsigned short)f2bf_rne(b.w);
  }
  *(s16x8*)(wsB + (size_t)idx * 8) = *(s16x8*)v;
}

// ---- main kernel ----
// A slot load: two 16-row phases (one per m-frag), lane-contiguous 32B each:
// phase p covers rows m0+16p+(lane>>2), floats (ks*32)+(lane&3)*8 .. +8.
#define ALOAD(ks) do { if ((ks) < KSTEPS) {                        \
    const int s_ = (ks) % 5, o_ = (ks) * 32;                       \
    abuf[s_][0][0] = *(const float4*)(pA0 + o_);                   \
    abuf[s_][0][1] = *(const float4*)(pA0 + o_ + 4);               \
    abuf[s_][1][0] = *(const float4*)(pA1 + o_);                   \
    abuf[s_][1][1] = *(const float4*)(pA1 + o_ + 4);               \
  } } while (0)

#define BLOAD_WS(ks) do { if ((ks) < KSTEPS) {                     \
    _Pragma("unroll")                                              \
    for (int nt_ = 0; nt_ < NT; ++nt_)                             \
      bbuf[(ks) % 3][nt_] = pWS[(ks) * NT * 64 + nt_ * 64 + lane]; \
  } } while (0)

#define BLOAD_FB(ks) do { if ((ks) < KSTEPS) {                     \
    _Pragma("unroll")                                              \
    for (int nt_ = 0; nt_ < 4; ++nt_) {                            \
      fbf[(ks) & 1][nt_][0] = *(const float4*)(pB[nt_] + (ks)*32); \
      fbf[(ks) & 1][nt_][1] = *(const float4*)(pB[nt_] + (ks)*32 + 4); \
    }                                                              \
    if (b4ok) {                                                    \
      fbf[(ks) & 1][4][0] = *(const float4*)(pB[4] + (ks)*32);     \
      fbf[(ks) & 1][4][1] = *(const float4*)(pB[4] + (ks)*32 + 4); \
    } else {                                                       \
      fbf[(ks) & 1][4][0] = make_float4(0.f,0.f,0.f,0.f);          \
      fbf[(ks) & 1][4][1] = make_float4(0.f,0.f,0.f,0.f);          \
    }                                                              \
  } } while (0)

template <bool USE_WS>
__global__ __launch_bounds__(64, 2)
void tagging_main(const float* __restrict__ hs, const float* __restrict__ W,
                  const float* __restrict__ bias,
                  const i32x4* __restrict__ pWS, float* __restrict__ out) {
  __shared__ float lg[32][85];        // stride 85 (gcd(85,32)=1): softmax
                                      // column reads conflict-free

  const int lane = threadIdx.x;       // one wave per block
  const int m0   = blockIdx.x * 32;   // 66048/32 = 2064 blocks, exact

  const float* pA0 = hs + (size_t)(m0 + (lane >> 2)) * HD + (lane & 3) * 8;
  const float* pA1 = pA0 + 16 * HD;
  // bpermute byte addr: target lane t pulls src lane 4*(t&15) + (t>>4)
  const int bp = ((lane & 15) * 4 + (lane >> 4)) * 4;

  // fallback B pointers (fragment-order scatter, only if !USE_WS)
  const float* pB[NT];
  #pragma unroll
  for (int nt = 0; nt < NT; ++nt)
    pB[nt] = W + (size_t)(nt * 16 + (lane & 15)) * HD + (lane >> 4) * 8;
  const bool b4ok = (lane & 15) < 8;

  f32x4  acc[2][NT] = {};             // 40 VGPR
  float4 abuf[5][2][2];               // A depth-4 (5 slots, 80 VGPR)
  i32x4  bbuf[3][NT];                 // B depth-2 (3 slots, 60 VGPR, ws path)
  float4 fbf[2][NT][2];               // B depth-1 (fallback path)

  ALOAD(0); ALOAD(1); ALOAD(2); ALOAD(3);
  if constexpr (USE_WS) { BLOAD_WS(0); BLOAD_WS(1); } else { BLOAD_FB(0); }

  #pragma unroll
  for (int ks = 0; ks < KSTEPS; ++ks) {
    ALOAD(ks + 4);
    if constexpr (USE_WS) { BLOAD_WS(ks + 2); } else { BLOAD_FB(ks + 1); }

    s16x8 af[2];
    #pragma unroll
    for (int mt = 0; mt < 2; ++mt) {
      float4 a0 = abuf[ks % 5][mt][0], a1 = abuf[ks % 5][mt][1];
      i32x4 av;
      av[0] = __builtin_amdgcn_ds_bpermute(bp, pack2(a0.x, a0.y));
      av[1] = __builtin_amdgcn_ds_bpermute(bp, pack2(a0.z, a0.w));
      av[2] = __builtin_amdgcn_ds_bpermute(bp, pack2(a1.x, a1.y));
      av[3] = __builtin_amdgcn_ds_bpermute(bp, pack2(a1.z, a1.w));
      af[mt] = __builtin_bit_cast(s16x8, av);
    }

    #pragma unroll
    for (int nt = 0; nt < NT; ++nt) {
      s16x8 bf;
      if constexpr (USE_WS) {
        bf = __builtin_bit_cast(s16x8, bbuf[ks % 3][nt]);
      } else {
        float4 b0 = fbf[ks & 1][nt][0], b1 = fbf[ks & 1][nt][1];
        i32x4 bv;
        bv[0] = pack2(b0.x, b0.y); bv[1] = pack2(b0.z, b0.w);
        bv[2] = pack2(b1.x, b1.y); bv[3] = pack2(b1.z, b1.w);
        bf = __builtin_bit_cast(s16x8, bv);
      }
      acc[0][nt] = __builtin_amdgcn_mfma_f32_16x16x32_bf16(af[0], bf, acc[0][nt], 0, 0, 0);
      acc[1][nt] = __builtin_amdgcn_mfma_f32_16x16x32_bf16(af[1], bf, acc[1][nt], 0, 0, 0);
    }
  }

  // ---- epilogue: wave-private LDS transpose + 3-wide softmax ----
  #pragma unroll
  for (int mt = 0; mt < 2; ++mt)
    #pragma unroll
    for (int nt = 0; nt < NT; ++nt)
      #pragma unroll
      for (int j = 0; j < 4; ++j)   // C/D: col = lane&15, row = 4*(lane>>4)+j
        lg[mt * 16 + (lane >> 4) * 4 + j][nt * 16 + (lane & 15)] = acc[mt][nt][j];
  __syncthreads();                  // single wave: just the lgkmcnt drain

  const int bidx = m0 / LSEQ;       // block-uniform: 8256 % 32 == 0
  const int l0   = m0 - bidx * LSEQ;
  #pragma unroll
  for (int it = 0; it < 12; ++it) {
    int flat = it * 64 + lane;      // [0,768) = 24 relations x 32 tokens
    int g    = flat >> 5;           // relation, half-wave-uniform
    int tokl = flat & 31;
    float x0 = lg[tokl][3 * g + 0] + bias[3 * g + 0];
    float x1 = lg[tokl][3 * g + 1] + bias[3 * g + 1];
    float x2 = lg[tokl][3 * g + 2] + bias[3 * g + 2];
    float mx = fmaxf(x0, fmaxf(x1, x2));
    float e0 = __expf(x0 - mx), e1 = __expf(x1 - mx), e2 = __expf(x2 - mx);
    float inv = 1.0f / (e0 + e1 + e2);
    size_t o = ((size_t)(bidx * RREL + g) * LSEQ + l0 + tokl) * 3;
    out[o + 0] = e0 * inv;
    out[o + 1] = e1 * inv;
    out[o + 2] = e2 * inv;
  }
}

extern "C" void kernel_launch(void* const* d_in, const int* in_sizes, int n_in,
                              void* d_out, int out_size, void* d_ws, size_t ws_size,
                              hipStream_t stream) {
  (void)in_sizes; (void)n_in; (void)out_size;
  const float* hs   = (const float*)d_in[0];  // (8, 8256, 768) fp32
  const float* W    = (const float*)d_in[1];  // (24, 3, 768)   fp32
  const float* bias = (const float*)d_in[2];  // (24, 3)        fp32
  float* out = (float*)d_out;                 // (8, 24, 8256, 3) fp32

  const size_t needB = (size_t)KSTEPS * NT * 64 * 8 * 2;   // 122880 B
  if (d_ws && ws_size >= needB) {
    hipLaunchKernelGGL(conv_w_kernel, dim3(30), dim3(256), 0, stream,
                       W, (unsigned short*)d_ws);
    hipLaunchKernelGGL((tagging_main<true>), dim3(2064), dim3(64), 0, stream,
                       hs, W, bias, (const i32x4*)d_ws, out);
  } else {
    hipLaunchKernelGGL((tagging_main<false>), dim3(2064), dim3(64), 0, stream,
                       hs, W, bias, nullptr, out);
  }
}